// Round 2
// baseline (491.691 us; speedup 1.0000x reference)
//
#include <hip/hip_runtime.h>
#include <math.h>

#define WS_STRIDE 260     // per-graph accum: 256 num + 1 denom (+pad)
#define ACC_STRIDE 257    // per-graph slots in LDS accumulator
#define NODE_STRIDE 27    // per-node LDS slot stride (26 used, odd -> conflict-free)
#define MAXG 8            // max graphs tracked in LDS per block (fallback: global atomics)

__device__ __forceinline__ float dot4f(float4 a, float4 b){
  return a.x*b.x + a.y*b.y + a.z*b.z + a.w*b.w;
}
__device__ __forceinline__ float gelu_exact(float x){
  return 0.5f*x*(1.0f+erff(x*0.70710678118654752440f));
}
__device__ __forceinline__ void mm44(float o[4][4], const float a[4][4], const float b[4][4]){
  #pragma unroll
  for (int i=0;i<4;++i){
    #pragma unroll
    for (int j=0;j<4;++j)
      o[i][j] = a[i][0]*b[0][j] + a[i][1]*b[1][j] + a[i][2]*b[2][j] + a[i][3]*b[3][j];
  }
}

// one Jacobi rotation in plane (P,Q), other indices K1,K2 (compile-time)
template<int P,int Q,int K1,int K2>
__device__ __forceinline__ void jrot(float a[4][4], float V[4][4]){
  float apq = a[P][Q];
  if (fabsf(apq) > 1e-30f){
    float app=a[P][P], aqq=a[Q][Q];
    float tau=(aqq-app)/(2.0f*apq);
    float t=copysignf(1.0f,tau)/(fabsf(tau)+sqrtf(1.0f+tau*tau));
    float c=1.0f/sqrtf(1.0f+t*t), s=t*c;
    float a1p=a[K1][P], a1q=a[K1][Q];
    a[K1][P]=c*a1p-s*a1q; a[P][K1]=a[K1][P];
    a[K1][Q]=s*a1p+c*a1q; a[Q][K1]=a[K1][Q];
    float a2p=a[K2][P], a2q=a[K2][Q];
    a[K2][P]=c*a2p-s*a2q; a[P][K2]=a[K2][P];
    a[K2][Q]=s*a2p+c*a2q; a[Q][K2]=a[K2][Q];
    a[P][P]=app-t*apq; a[Q][Q]=aqq+t*apq; a[P][Q]=0.0f; a[Q][P]=0.0f;
    #pragma unroll
    for (int r=0;r<4;++r){ float vp=V[r][P], vq=V[r][Q]; V[r][P]=c*vp-s*vq; V[r][Q]=s*vp+c*vq; }
  }
}

__device__ __forceinline__ void jacobi4(float a[4][4], float V[4][4], int sweeps){
  #pragma unroll
  for (int i=0;i<4;++i){
    #pragma unroll
    for (int j=0;j<4;++j) V[i][j] = (i==j)?1.0f:0.0f;
  }
  for (int sw=0; sw<sweeps; ++sw){
    jrot<0,1,2,3>(a,V); jrot<0,2,1,3>(a,V); jrot<0,3,1,2>(a,V);
    jrot<1,2,0,3>(a,V); jrot<1,3,0,2>(a,V); jrot<2,3,0,1>(a,V);
  }
}

__device__ __forceinline__ float det4(const float V[4][4]){
  float s0 = V[0][0]*V[1][1] - V[0][1]*V[1][0];
  float s1 = V[0][0]*V[1][2] - V[0][2]*V[1][0];
  float s2 = V[0][0]*V[1][3] - V[0][3]*V[1][0];
  float s3 = V[0][1]*V[1][2] - V[0][2]*V[1][1];
  float s4 = V[0][1]*V[1][3] - V[0][3]*V[1][1];
  float s5 = V[0][2]*V[1][3] - V[0][3]*V[1][2];
  float c5 = V[2][2]*V[3][3] - V[2][3]*V[3][2];
  float c4 = V[2][1]*V[3][3] - V[2][3]*V[3][1];
  float c3 = V[2][1]*V[3][2] - V[2][2]*V[3][1];
  float c2 = V[2][0]*V[3][3] - V[2][3]*V[3][0];
  float c1 = V[2][0]*V[3][2] - V[2][2]*V[3][0];
  float c0 = V[2][0]*V[3][1] - V[2][1]*V[3][0];
  return s0*c5 - s1*c4 + s2*c3 + s3*c2 - s4*c1 + s5*c0;
}

// ---------------- Kernel A: S,G -> Newton-Schulz whiten + Procrustes -> (W,T) ----------------
__global__ __launch_bounds__(256, 4) void whiten_kernel(
    const float* __restrict__ H, const float* __restrict__ anchor,
    float* __restrict__ wsT, int N)
{
  __shared__ float nodeMat[256*NODE_STRIDE];
  __shared__ float aL[256];

  const int tid = threadIdx.x;
  const int n0 = blockIdx.x * 256;
  const int iq = tid & 3;
  const int nq = tid >> 2;

  aL[tid]=anchor[tid];
  __syncthreads();

  // ---- Phase 1: S = H H^T (packed 10), G = anchor H^T (16) ----
  for (int p=0;p<4;++p){
    int nodeL = p*64 + nq;
    int node  = n0 + nodeL;
    if (node < N){
      const float* Hn = H + (size_t)node*256;
      float S[10], G[16];
      #pragma unroll
      for (int r=0;r<10;++r) S[r]=0.0f;
      #pragma unroll
      for (int r=0;r<16;++r) G[r]=0.0f;
      #pragma unroll
      for (int j=0;j<4;++j){
        float4 h0 = *(const float4*)(Hn + 0*64 + j*16 + iq*4);
        float4 h1v= *(const float4*)(Hn + 1*64 + j*16 + iq*4);
        float4 h2 = *(const float4*)(Hn + 2*64 + j*16 + iq*4);
        float4 h3 = *(const float4*)(Hn + 3*64 + j*16 + iq*4);
        float4 a0 = *(const float4*)(aL + 0*64 + j*16 + iq*4);
        float4 a1 = *(const float4*)(aL + 1*64 + j*16 + iq*4);
        float4 a2 = *(const float4*)(aL + 2*64 + j*16 + iq*4);
        float4 a3 = *(const float4*)(aL + 3*64 + j*16 + iq*4);
        S[0]+=dot4f(h0,h0); S[1]+=dot4f(h0,h1v); S[2]+=dot4f(h0,h2); S[3]+=dot4f(h0,h3);
        S[4]+=dot4f(h1v,h1v); S[5]+=dot4f(h1v,h2); S[6]+=dot4f(h1v,h3);
        S[7]+=dot4f(h2,h2); S[8]+=dot4f(h2,h3); S[9]+=dot4f(h3,h3);
        G[0]+=dot4f(a0,h0);  G[1]+=dot4f(a0,h1v);  G[2]+=dot4f(a0,h2);  G[3]+=dot4f(a0,h3);
        G[4]+=dot4f(a1,h0);  G[5]+=dot4f(a1,h1v);  G[6]+=dot4f(a1,h2);  G[7]+=dot4f(a1,h3);
        G[8]+=dot4f(a2,h0);  G[9]+=dot4f(a2,h1v);  G[10]+=dot4f(a2,h2); G[11]+=dot4f(a2,h3);
        G[12]+=dot4f(a3,h0); G[13]+=dot4f(a3,h1v); G[14]+=dot4f(a3,h2); G[15]+=dot4f(a3,h3);
      }
      #pragma unroll
      for (int r=0;r<10;++r){ S[r]+=__shfl_xor(S[r],1); S[r]+=__shfl_xor(S[r],2); }
      #pragma unroll
      for (int r=0;r<16;++r){ G[r]+=__shfl_xor(G[r],1); G[r]+=__shfl_xor(G[r],2); }
      if (iq==0){
        float* dst = nodeMat + nodeL*NODE_STRIDE;
        #pragma unroll
        for (int r=0;r<10;++r) dst[r]=S[r];
        #pragma unroll
        for (int r=0;r<16;++r) dst[10+r]=G[r];
      }
    }
  }
  __syncthreads();

  // ---- Phase 2: Newton-Schulz S^{-1/2}, Jacobi SVD for Procrustes ----
  {
    int node = n0 + tid;
    if (node < N){
      float* slot = nodeMat + tid*NODE_STRIDE;
      float a[4][4];
      a[0][0]=slot[0]+1e-4f; a[0][1]=a[1][0]=slot[1]; a[0][2]=a[2][0]=slot[2]; a[0][3]=a[3][0]=slot[3];
      a[1][1]=slot[4]+1e-4f; a[1][2]=a[2][1]=slot[5]; a[1][3]=a[3][1]=slot[6];
      a[2][2]=slot[7]+1e-4f; a[2][3]=a[3][2]=slot[8]; a[3][3]=slot[9]+1e-4f;
      float Gm[4][4];
      #pragma unroll
      for (int d=0;d<4;++d){
        #pragma unroll
        for (int f=0;f<4;++f) Gm[d][f]=slot[10+4*d+f];
      }
      // Newton-Schulz coupled iteration: Z -> (S/c)^{-1/2}
      float cs = 0.4f*(a[0][0]+a[1][1]+a[2][2]+a[3][3]);
      float rc = 1.0f/cs;
      float Y[4][4], Z[4][4];
      #pragma unroll
      for (int i=0;i<4;++i){
        #pragma unroll
        for (int j=0;j<4;++j){ Y[i][j]=a[i][j]*rc; Z[i][j]=(i==j)?1.0f:0.0f; }
      }
      #pragma unroll
      for (int it=0; it<8; ++it){
        float P[4][4], T[4][4], Y2[4][4], Z2[4][4];
        mm44(P, Z, Y);
        #pragma unroll
        for (int i=0;i<4;++i){
          #pragma unroll
          for (int j=0;j<4;++j) T[i][j] = (i==j) ? 1.5f-0.5f*P[i][j] : -0.5f*P[i][j];
        }
        mm44(Y2, Y, T);
        mm44(Z2, T, Z);
        #pragma unroll
        for (int i=0;i<4;++i){
          #pragma unroll
          for (int j=0;j<4;++j){ Y[i][j]=Y2[i][j]; Z[i][j]=Z2[i][j]; }
        }
      }
      float rsc = rsqrtf(cs);
      float Wm[4][4];
      #pragma unroll
      for (int i=0;i<4;++i){
        #pragma unroll
        for (int j=0;j<4;++j) Wm[i][j] = Z[i][j]*rsc;
      }
      // M = G * W ; A2 = M^T M
      float M[4][4];
      mm44(M, Gm, Wm);
      float A2[4][4];
      #pragma unroll
      for (int i=0;i<4;++i){
        #pragma unroll
        for (int j=0;j<4;++j)
          A2[i][j] = M[0][i]*M[0][j] + M[1][i]*M[1][j] + M[2][i]*M[2][j] + M[3][i]*M[3][j];
      }
      float V2[4][4];
      jacobi4(A2, V2, 4);
      float mu[4];
      #pragma unroll
      for (int i=0;i<4;++i) mu[i]=A2[i][i];
      #define CSW(I,J) if (mu[I] < mu[J]) { float tw; \
        tw=mu[I]; mu[I]=mu[J]; mu[J]=tw; \
        tw=V2[0][I]; V2[0][I]=V2[0][J]; V2[0][J]=tw; \
        tw=V2[1][I]; V2[1][I]=V2[1][J]; V2[1][J]=tw; \
        tw=V2[2][I]; V2[2][I]=V2[2][J]; V2[2][J]=tw; \
        tw=V2[3][I]; V2[3][I]=V2[3][J]; V2[3][J]=tw; }
      CSW(0,1) CSW(2,3) CSW(0,2) CSW(1,3) CSW(1,2)
      #undef CSW
      float u0[4],u1[4],u2[4];
      #pragma unroll
      for (int d=0;d<4;++d){
        u0[d]=M[d][0]*V2[0][0]+M[d][1]*V2[1][0]+M[d][2]*V2[2][0]+M[d][3]*V2[3][0];
        u1[d]=M[d][0]*V2[0][1]+M[d][1]*V2[1][1]+M[d][2]*V2[2][1]+M[d][3]*V2[3][1];
        u2[d]=M[d][0]*V2[0][2]+M[d][1]*V2[1][2]+M[d][2]*V2[2][2]+M[d][3]*V2[3][2];
      }
      {
        float dd = u0[0]*u0[0]+u0[1]*u0[1]+u0[2]*u0[2]+u0[3]*u0[3];
        float in0 = 1.0f/sqrtf(fmaxf(dd,1e-30f));
        #pragma unroll
        for (int d=0;d<4;++d) u0[d]*=in0;
        float p01 = u0[0]*u1[0]+u0[1]*u1[1]+u0[2]*u1[2]+u0[3]*u1[3];
        #pragma unroll
        for (int d=0;d<4;++d) u1[d]-=p01*u0[d];
        dd = u1[0]*u1[0]+u1[1]*u1[1]+u1[2]*u1[2]+u1[3]*u1[3];
        float in1 = 1.0f/sqrtf(fmaxf(dd,1e-30f));
        #pragma unroll
        for (int d=0;d<4;++d) u1[d]*=in1;
        float p02 = u0[0]*u2[0]+u0[1]*u2[1]+u0[2]*u2[2]+u0[3]*u2[3];
        float p12 = u1[0]*u2[0]+u1[1]*u2[1]+u1[2]*u2[2]+u1[3]*u2[3];
        #pragma unroll
        for (int d=0;d<4;++d) u2[d]-=p02*u0[d]+p12*u1[d];
        dd = u2[0]*u2[0]+u2[1]*u2[1]+u2[2]*u2[2]+u2[3]*u2[3];
        float in2 = 1.0f/sqrtf(fmaxf(dd,1e-30f));
        #pragma unroll
        for (int d=0;d<4;++d) u2[d]*=in2;
      }
      #define D3(p,q,r) (u0[p]*(u1[q]*u2[r]-u1[r]*u2[q]) - u1[p]*(u0[q]*u2[r]-u0[r]*u2[q]) + u2[p]*(u0[q]*u1[r]-u0[r]*u1[q]))
      float t3[4];
      t3[0] = -D3(1,2,3); t3[1] = D3(0,2,3); t3[2] = -D3(0,1,3); t3[3] = D3(0,1,2);
      #undef D3
      float dl = (det4(V2) >= 0.0f) ? 1.0f : -1.0f;
      float R[4][4];
      #pragma unroll
      for (int d=0;d<4;++d){
        #pragma unroll
        for (int e=0;e<4;++e)
          R[d][e] = u0[d]*V2[e][0] + u1[d]*V2[e][1] + u2[d]*V2[e][2] + dl*t3[d]*V2[e][3];
      }
      float T[4][4];
      mm44(T, R, Wm);
      slot[0]=Wm[0][0]; slot[1]=Wm[0][1]; slot[2]=Wm[0][2]; slot[3]=Wm[0][3];
      slot[4]=Wm[1][1]; slot[5]=Wm[1][2]; slot[6]=Wm[1][3];
      slot[7]=Wm[2][2]; slot[8]=Wm[2][3]; slot[9]=Wm[3][3];
      #pragma unroll
      for (int d=0;d<4;++d){
        #pragma unroll
        for (int e=0;e<4;++e) slot[10+4*d+e]=T[d][e];
      }
    }
  }
  __syncthreads();

  // ---- coalesced write-out: 28 floats per node (26 used) ----
  {
    int nlim = N - n0; if (nlim > 256) nlim = 256;
    for (int L=tid; L<256*28; L+=256){
      int n = L/28, r = L - n*28;
      if (n < nlim){
        float v = (r < 26) ? nodeMat[n*NODE_STRIDE + r] : 0.0f;
        wsT[(size_t)n0*28 + L] = v;
      }
    }
  }
}

// ---------------- Kernel B: u, score, softmax-weighted pooling ----------------
__global__ __launch_bounds__(256, 4) void pool_kernel(
    const float* __restrict__ H, const int* __restrict__ batch,
    const float* __restrict__ wsT, const float* __restrict__ w1g,
    const float* __restrict__ b1, const float* __restrict__ w2,
    const float* __restrict__ b2, float* __restrict__ wsAcc, int N)
{
  __shared__ float w1L[64*64];
  __shared__ float accL[MAXG*ACC_STRIDE];
  __shared__ float b1L[64];
  __shared__ float w2L[64];

  const int tid = threadIdx.x;
  const int n0 = blockIdx.x * 256;
  const int iq = tid & 3;
  const int nq = tid >> 2;

  for (int i=tid;i<4096;i+=256) w1L[i]=w1g[i];
  if (tid < 64){ b1L[tid]=b1[tid]; w2L[tid]=w2[tid]; }
  for (int i=tid;i<MAXG*ACC_STRIDE;i+=256) accL[i]=0.0f;
  __syncthreads();

  const float b2v = b2[0];
  const int gFirst = batch[n0];

  for (int p=0;p<4;++p){
    int nodeL = p*64 + nq;
    int node  = n0 + nodeL;
    if (node < N){
      // load per-node W (sym, 10) and T (16) -- quad lanes redundant, L1-broadcast
      const float4* wtp = (const float4*)(wsT + (size_t)node*28);
      float wt[28];
      #pragma unroll
      for (int i=0;i<7;++i){
        float4 t = wtp[i];
        wt[4*i]=t.x; wt[4*i+1]=t.y; wt[4*i+2]=t.z; wt[4*i+3]=t.w;
      }
      float Wm[4][4], T[4][4];
      Wm[0][0]=wt[0]; Wm[0][1]=Wm[1][0]=wt[1]; Wm[0][2]=Wm[2][0]=wt[2]; Wm[0][3]=Wm[3][0]=wt[3];
      Wm[1][1]=wt[4]; Wm[1][2]=Wm[2][1]=wt[5]; Wm[1][3]=Wm[3][1]=wt[6];
      Wm[2][2]=wt[7]; Wm[2][3]=Wm[3][2]=wt[8]; Wm[3][3]=wt[9];
      #pragma unroll
      for (int d=0;d<4;++d){
        #pragma unroll
        for (int e=0;e<4;++e) T[d][e]=wt[10+4*d+e];
      }
      const float* Hn = H + (size_t)node*256;
      float h[4][16];
      #pragma unroll
      for (int d=0;d<4;++d){
        #pragma unroll
        for (int j=0;j<4;++j){
          float4 t = *(const float4*)(Hn + d*64 + j*16 + iq*4);
          h[d][4*j+0]=t.x; h[d][4*j+1]=t.y; h[d][4*j+2]=t.z; h[d][4*j+3]=t.w;
        }
      }
      float u[16];
      #pragma unroll
      for (int col=0; col<16; ++col){
        float x0=h[0][col], x1=h[1][col], x2=h[2][col], x3=h[3][col];
        float wv0 = Wm[0][0]*x0+Wm[0][1]*x1+Wm[0][2]*x2+Wm[0][3]*x3;
        float wv1 = Wm[1][0]*x0+Wm[1][1]*x1+Wm[1][2]*x2+Wm[1][3]*x3;
        float wv2 = Wm[2][0]*x0+Wm[2][1]*x1+Wm[2][2]*x2+Wm[2][3]*x3;
        float wv3 = Wm[3][0]*x0+Wm[3][1]*x1+Wm[3][2]*x2+Wm[3][3]*x3;
        u[col] = wv0*wv0+wv1*wv1+wv2*wv2+wv3*wv3;
        float z0 = T[0][0]*x0+T[0][1]*x1+T[0][2]*x2+T[0][3]*x3;
        float z1 = T[1][0]*x0+T[1][1]*x1+T[1][2]*x2+T[1][3]*x3;
        float z2 = T[2][0]*x0+T[2][1]*x1+T[2][2]*x2+T[2][3]*x3;
        float z3 = T[3][0]*x0+T[3][1]*x1+T[3][2]*x2+T[3][3]*x3;
        h[0][col]=z0; h[1][col]=z1; h[2][col]=z2; h[3][col]=z3;  // h now holds Za
      }
      float h1[16];
      #pragma unroll
      for (int kk=0;kk<16;++kk) h1[kk]=b1L[iq*16+kk];
      for (int m=0;m<4;++m){
        int qq = iq ^ m;
        #pragma unroll
        for (int jl=0;jl<16;++jl){
          float uu = __shfl_xor(u[jl], m);
          int c = 16*(jl>>2) + 4*qq + (jl&3);
          const float* wr = w1L + c*64 + iq*16;
          float4 wA=*(const float4*)(wr);
          float4 wB=*(const float4*)(wr+4);
          float4 wC=*(const float4*)(wr+8);
          float4 wD=*(const float4*)(wr+12);
          h1[0]+=uu*wA.x; h1[1]+=uu*wA.y; h1[2]+=uu*wA.z; h1[3]+=uu*wA.w;
          h1[4]+=uu*wB.x; h1[5]+=uu*wB.y; h1[6]+=uu*wB.z; h1[7]+=uu*wB.w;
          h1[8]+=uu*wC.x; h1[9]+=uu*wC.y; h1[10]+=uu*wC.z; h1[11]+=uu*wC.w;
          h1[12]+=uu*wD.x; h1[13]+=uu*wD.y; h1[14]+=uu*wD.z; h1[15]+=uu*wD.w;
        }
      }
      float sp = 0.0f;
      #pragma unroll
      for (int kk=0;kk<16;++kk) sp += gelu_exact(h1[kk]) * w2L[iq*16+kk];
      sp += __shfl_xor(sp,1); sp += __shfl_xor(sp,2);
      float e = expf(sp + b2v);   // scores tiny -> no-max-shift softmax safe

      int g  = batch[node];
      int gl = g - gFirst;
      if (gl < MAXG){
        float* acc = accL + gl*ACC_STRIDE;
        #pragma unroll
        for (int dd=0;dd<4;++dd){
          int dsel = (nq + dd) & 3;
          #pragma unroll
          for (int col=0;col<16;++col){
            float v0=h[0][col], v1=h[1][col], v2=h[2][col], v3=h[3][col];
            float v = (dsel==0)?v0 : (dsel==1)?v1 : (dsel==2)?v2 : v3;
            int c = 16*(col>>2) + 4*iq + (col&3);
            atomicAdd(acc + dsel*64 + c, e*v);
          }
        }
        if (iq==0) atomicAdd(acc + 256, e);
      } else {
        float* wsg = wsAcc + (size_t)g*WS_STRIDE;
        #pragma unroll
        for (int dd=0;dd<4;++dd){
          #pragma unroll
          for (int col=0;col<16;++col){
            int c = 16*(col>>2) + 4*iq + (col&3);
            atomicAdd(wsg + dd*64 + c, e*h[dd][col]);
          }
        }
        if (iq==0) atomicAdd(wsg + 256, e);
      }
    }
  }
  __syncthreads();

  {
    int lastIdx = n0+255 < N ? n0+255 : N-1;
    int gLast = batch[lastIdx];
    int ngl = gLast - gFirst + 1; if (ngl > MAXG) ngl = MAXG;
    for (int idx=tid; idx<ngl*ACC_STRIDE; idx+=256){
      int gl = idx / ACC_STRIDE;
      int sl = idx - gl*ACC_STRIDE;
      float v = accL[idx];
      if (v != 0.0f) atomicAdd(wsAcc + (size_t)(gFirst+gl)*WS_STRIDE + sl, v);
    }
  }
}

// ---------------- Kernel C: per-graph MLP + LayerNorm + reduce ----------------
__global__ __launch_bounds__(256) void finalize_kernel(
    const float* __restrict__ wsAcc, const float* __restrict__ token,
    const float* __restrict__ wc1, const float* __restrict__ bc1,
    const float* __restrict__ wc2, const float* __restrict__ bc2,
    const float* __restrict__ lng, const float* __restrict__ lnb,
    float* __restrict__ out)
{
  __shared__ float comb[4][128];
  __shared__ float hcL[4][64];
  __shared__ float upsq[4][64];
  const int g = blockIdx.x, tid = threadIdx.x;
  const int d = tid >> 6, k = tid & 63;
  const float* wsg = wsAcc + (size_t)g*WS_STRIDE;
  float denom = wsg[256];
  float inv = (denom != 0.0f) ? 1.0f/denom : 0.0f;
  for (int i=tid;i<512;i+=256){
    int dd=i>>7, j=i&127;
    comb[dd][j] = (j<64) ? token[dd*64+j] : wsg[dd*64+(j-64)]*inv;
  }
  __syncthreads();
  float acc = bc1[k];
  for (int j=0;j<128;++j) acc += comb[d][j]*wc1[j*64+k];
  hcL[d][k] = gelu_exact(acc);
  __syncthreads();
  float acc2 = bc2[k];
  for (int j=0;j<64;++j) acc2 += hcL[d][j]*wc2[j*64+k];
  float s1 = acc2, s2 = acc2*acc2;
  #pragma unroll
  for (int m=1;m<64;m<<=1){ s1 += __shfl_xor(s1,m); s2 += __shfl_xor(s2,m); }
  float mu  = s1*(1.0f/64.0f);
  float var = s2*(1.0f/64.0f) - mu*mu;
  float up = (acc2 - mu)*(1.0f/sqrtf(var + 1e-5f))*lng[k] + lnb[k];
  upsq[d][k] = up*up;
  __syncthreads();
  if (tid < 64)
    out[(size_t)g*64 + tid] = upsq[0][tid]+upsq[1][tid]+upsq[2][tid]+upsq[3][tid];
}

extern "C" void kernel_launch(void* const* d_in, const int* in_sizes, int n_in,
                              void* d_out, int out_size, void* d_ws, size_t ws_size,
                              hipStream_t stream) {
  (void)n_in; (void)ws_size;
  const float* H      = (const float*)d_in[0];
  const int*   batch  = (const int*)  d_in[1];
  const float* anchor = (const float*)d_in[3];
  const float* w1     = (const float*)d_in[4];
  const float* b1     = (const float*)d_in[5];
  const float* w2     = (const float*)d_in[6];
  const float* b2     = (const float*)d_in[7];
  const float* token  = (const float*)d_in[8];
  const float* wc1    = (const float*)d_in[9];
  const float* bc1    = (const float*)d_in[10];
  const float* wc2    = (const float*)d_in[11];
  const float* bc2    = (const float*)d_in[12];
  const float* ln_g   = (const float*)d_in[13];
  const float* ln_b   = (const float*)d_in[14];
  float* out = (float*)d_out;

  const int N = in_sizes[0] / 256;   // nodes
  const int B = out_size / 64;       // graphs
  const int nb = (N + 255)/256;

  float* wsAcc = (float*)d_ws;                    // B*WS_STRIDE floats
  float* wsT   = wsAcc + (size_t)B*WS_STRIDE;     // nb*256*28 floats

  hipMemsetAsync(wsAcc, 0, (size_t)B*WS_STRIDE*sizeof(float), stream);
  whiten_kernel<<<nb, 256, 0, stream>>>(H, anchor, wsT, N);
  pool_kernel<<<nb, 256, 0, stream>>>(H, batch, wsT, w1, b1, w2, b2, wsAcc, N);
  finalize_kernel<<<B, 256, 0, stream>>>(wsAcc, token, wc1, bc1, wc2, bc2, ln_g, ln_b, out);
}

// Round 3
// 442.687 us; speedup vs baseline: 1.1107x; 1.1107x over previous
//
#include <hip/hip_runtime.h>
#include <math.h>

#define WSG_STRIDE 260    // per-graph accum: 256 num + 1 denom (+pad)
#define ACC_STRIDE 257    // per-graph slots in LDS accumulator
#define NODE_STRIDE 27    // per-node LDS slot stride (26 used, odd -> conflict-free)
#define MAXG 4            // max graphs tracked in LDS per 64-node block
#define NPB 64            // nodes per block

__device__ __forceinline__ float dot4f(float4 a, float4 b){
  return a.x*b.x + a.y*b.y + a.z*b.z + a.w*b.w;
}
__device__ __forceinline__ float gelu_exact(float x){
  return 0.5f*x*(1.0f+erff(x*0.70710678118654752440f));
}
__device__ __forceinline__ void mm44(float o[4][4], const float a[4][4], const float b[4][4]){
  #pragma unroll
  for (int i=0;i<4;++i){
    #pragma unroll
    for (int j=0;j<4;++j)
      o[i][j] = a[i][0]*b[0][j] + a[i][1]*b[1][j] + a[i][2]*b[2][j] + a[i][3]*b[3][j];
  }
}

template<int P,int Q,int K1,int K2>
__device__ __forceinline__ void jrot(float a[4][4], float V[4][4]){
  float apq = a[P][Q];
  if (fabsf(apq) > 1e-30f){
    float app=a[P][P], aqq=a[Q][Q];
    float tau=(aqq-app)/(2.0f*apq);
    float t=copysignf(1.0f,tau)/(fabsf(tau)+sqrtf(1.0f+tau*tau));
    float c=1.0f/sqrtf(1.0f+t*t), s=t*c;
    float a1p=a[K1][P], a1q=a[K1][Q];
    a[K1][P]=c*a1p-s*a1q; a[P][K1]=a[K1][P];
    a[K1][Q]=s*a1p+c*a1q; a[Q][K1]=a[K1][Q];
    float a2p=a[K2][P], a2q=a[K2][Q];
    a[K2][P]=c*a2p-s*a2q; a[P][K2]=a[K2][P];
    a[K2][Q]=s*a2p+c*a2q; a[Q][K2]=a[K2][Q];
    a[P][P]=app-t*apq; a[Q][Q]=aqq+t*apq; a[P][Q]=0.0f; a[Q][P]=0.0f;
    #pragma unroll
    for (int r=0;r<4;++r){ float vp=V[r][P], vq=V[r][Q]; V[r][P]=c*vp-s*vq; V[r][Q]=s*vp+c*vq; }
  }
}

__device__ __forceinline__ void jacobi4(float a[4][4], float V[4][4], int sweeps){
  #pragma unroll
  for (int i=0;i<4;++i){
    #pragma unroll
    for (int j=0;j<4;++j) V[i][j] = (i==j)?1.0f:0.0f;
  }
  for (int sw=0; sw<sweeps; ++sw){
    jrot<0,1,2,3>(a,V); jrot<0,2,1,3>(a,V); jrot<0,3,1,2>(a,V);
    jrot<1,2,0,3>(a,V); jrot<1,3,0,2>(a,V); jrot<2,3,0,1>(a,V);
  }
}

__device__ __forceinline__ float det4(const float V[4][4]){
  float s0 = V[0][0]*V[1][1] - V[0][1]*V[1][0];
  float s1 = V[0][0]*V[1][2] - V[0][2]*V[1][0];
  float s2 = V[0][0]*V[1][3] - V[0][3]*V[1][0];
  float s3 = V[0][1]*V[1][2] - V[0][2]*V[1][1];
  float s4 = V[0][1]*V[1][3] - V[0][3]*V[1][1];
  float s5 = V[0][2]*V[1][3] - V[0][3]*V[1][2];
  float c5 = V[2][2]*V[3][3] - V[2][3]*V[3][2];
  float c4 = V[2][1]*V[3][3] - V[2][3]*V[3][1];
  float c3 = V[2][1]*V[3][2] - V[2][2]*V[3][1];
  float c2 = V[2][0]*V[3][3] - V[2][3]*V[3][0];
  float c1 = V[2][0]*V[3][2] - V[2][2]*V[3][0];
  float c0 = V[2][0]*V[3][1] - V[2][1]*V[3][0];
  return s0*c5 - s1*c4 + s2*c3 + s3*c2 - s4*c1 + s5*c0;
}

// Fused: S,G -> NS whiten + Procrustes -> score -> softmax-weighted pooling.
// 64 nodes / 256-thread block => 2048 blocks (grid no longer the occupancy cap).
// waves_per_eu(4,4): pin 128 VGPRs so compiler doesn't shrink-and-spill.
__global__ __launch_bounds__(256, 4) __attribute__((amdgpu_waves_per_eu(4,4)))
void node_kernel(
    const float* __restrict__ H, const int* __restrict__ batch,
    const float* __restrict__ anchor, const float* __restrict__ w1g,
    const float* __restrict__ b1, const float* __restrict__ w2,
    const float* __restrict__ b2, float* __restrict__ wsAcc, int N)
{
  __shared__ float nodeMat[NPB*NODE_STRIDE]; // 6.9 KB
  __shared__ float w1L[4096];                // 16 KB
  __shared__ float accL[MAXG*ACC_STRIDE];    // 4.1 KB
  __shared__ float aL[256];
  __shared__ float b1L[64];
  __shared__ float w2L[64];

  const int tid = threadIdx.x;
  const int n0 = blockIdx.x * NPB;
  const int iq = tid & 3;        // quad lane (column-group owner)
  const int nq = tid >> 2;       // node index in block (0..63)

  // ---- staging ----
  for (int i=tid;i<4096;i+=256) w1L[i]=w1g[i];
  aL[tid]=anchor[tid];
  if (tid < 64){ b1L[tid]=b1[tid]; w2L[tid]=w2[tid]; }
  for (int i=tid;i<MAXG*ACC_STRIDE;i+=256) accL[i]=0.0f;
  __syncthreads();

  const int node = n0 + nq;
  const bool valid = node < N;

  // ---- Phase 1: S = H H^T (packed 10), G = anchor H^T (16) ----
  if (valid){
    const float* Hn = H + (size_t)node*256;
    float S[10], G[16];
    #pragma unroll
    for (int r=0;r<10;++r) S[r]=0.0f;
    #pragma unroll
    for (int r=0;r<16;++r) G[r]=0.0f;
    #pragma unroll
    for (int j=0;j<4;++j){
      float4 h0 = *(const float4*)(Hn + 0*64 + j*16 + iq*4);
      float4 h1v= *(const float4*)(Hn + 1*64 + j*16 + iq*4);
      float4 h2 = *(const float4*)(Hn + 2*64 + j*16 + iq*4);
      float4 h3 = *(const float4*)(Hn + 3*64 + j*16 + iq*4);
      float4 a0 = *(const float4*)(aL + 0*64 + j*16 + iq*4);
      float4 a1 = *(const float4*)(aL + 1*64 + j*16 + iq*4);
      float4 a2 = *(const float4*)(aL + 2*64 + j*16 + iq*4);
      float4 a3 = *(const float4*)(aL + 3*64 + j*16 + iq*4);
      S[0]+=dot4f(h0,h0); S[1]+=dot4f(h0,h1v); S[2]+=dot4f(h0,h2); S[3]+=dot4f(h0,h3);
      S[4]+=dot4f(h1v,h1v); S[5]+=dot4f(h1v,h2); S[6]+=dot4f(h1v,h3);
      S[7]+=dot4f(h2,h2); S[8]+=dot4f(h2,h3); S[9]+=dot4f(h3,h3);
      G[0]+=dot4f(a0,h0);  G[1]+=dot4f(a0,h1v);  G[2]+=dot4f(a0,h2);  G[3]+=dot4f(a0,h3);
      G[4]+=dot4f(a1,h0);  G[5]+=dot4f(a1,h1v);  G[6]+=dot4f(a1,h2);  G[7]+=dot4f(a1,h3);
      G[8]+=dot4f(a2,h0);  G[9]+=dot4f(a2,h1v);  G[10]+=dot4f(a2,h2); G[11]+=dot4f(a2,h3);
      G[12]+=dot4f(a3,h0); G[13]+=dot4f(a3,h1v); G[14]+=dot4f(a3,h2); G[15]+=dot4f(a3,h3);
    }
    #pragma unroll
    for (int r=0;r<10;++r){ S[r]+=__shfl_xor(S[r],1); S[r]+=__shfl_xor(S[r],2); }
    #pragma unroll
    for (int r=0;r<16;++r){ G[r]+=__shfl_xor(G[r],1); G[r]+=__shfl_xor(G[r],2); }
    if (iq==0){
      float* dst = nodeMat + nq*NODE_STRIDE;
      #pragma unroll
      for (int r=0;r<10;++r) dst[r]=S[r];
      #pragma unroll
      for (int r=0;r<16;++r) dst[10+r]=G[r];
    }
  }
  __syncthreads();

  // ---- Phase 2 (threads 0..63, one per node): NS S^{-1/2} + Jacobi-SVD Procrustes ----
  if (tid < NPB && (n0 + tid) < N){
    float* slot = nodeMat + tid*NODE_STRIDE;
    float a00=slot[0]+1e-4f, a01=slot[1], a02=slot[2], a03=slot[3];
    float a11=slot[4]+1e-4f, a12=slot[5], a13=slot[6];
    float a22=slot[7]+1e-4f, a23=slot[8], a33=slot[9]+1e-4f;
    float Gm[4][4];
    #pragma unroll
    for (int d=0;d<4;++d){
      #pragma unroll
      for (int f=0;f<4;++f) Gm[d][f]=slot[10+4*d+f];
    }
    // Newton-Schulz coupled iteration for (S/c)^{-1/2}
    float cs = 0.4f*(a00+a11+a22+a33);
    float rc = 1.0f/cs;
    float Y[4][4], Z[4][4];
    Y[0][0]=a00*rc; Y[0][1]=Y[1][0]=a01*rc; Y[0][2]=Y[2][0]=a02*rc; Y[0][3]=Y[3][0]=a03*rc;
    Y[1][1]=a11*rc; Y[1][2]=Y[2][1]=a12*rc; Y[1][3]=Y[3][1]=a13*rc;
    Y[2][2]=a22*rc; Y[2][3]=Y[3][2]=a23*rc; Y[3][3]=a33*rc;
    #pragma unroll
    for (int i=0;i<4;++i){
      #pragma unroll
      for (int j=0;j<4;++j) Z[i][j]=(i==j)?1.0f:0.0f;
    }
    #pragma unroll
    for (int it=0; it<8; ++it){
      float P[4][4], Y2[4][4], Z2[4][4];
      mm44(P, Z, Y);
      #pragma unroll
      for (int i=0;i<4;++i){
        #pragma unroll
        for (int j=0;j<4;++j) P[i][j] = (i==j) ? 1.5f-0.5f*P[i][j] : -0.5f*P[i][j];
      }
      mm44(Y2, Y, P);
      mm44(Z2, P, Z);
      #pragma unroll
      for (int i=0;i<4;++i){
        #pragma unroll
        for (int j=0;j<4;++j){ Y[i][j]=Y2[i][j]; Z[i][j]=Z2[i][j]; }
      }
    }
    float rsc = rsqrtf(cs);
    float Wm[4][4];
    #pragma unroll
    for (int i=0;i<4;++i){
      #pragma unroll
      for (int j=0;j<4;++j) Wm[i][j] = Z[i][j]*rsc;
    }
    float M[4][4];
    mm44(M, Gm, Wm);
    // park Wm in LDS (frees regs through the SVD); reload for T at the end
    slot[0]=Wm[0][0]; slot[1]=Wm[0][1]; slot[2]=Wm[0][2]; slot[3]=Wm[0][3];
    slot[4]=Wm[1][1]; slot[5]=Wm[1][2]; slot[6]=Wm[1][3];
    slot[7]=Wm[2][2]; slot[8]=Wm[2][3]; slot[9]=Wm[3][3];
    float A2[4][4];
    #pragma unroll
    for (int i=0;i<4;++i){
      #pragma unroll
      for (int j=0;j<4;++j)
        A2[i][j] = M[0][i]*M[0][j] + M[1][i]*M[1][j] + M[2][i]*M[2][j] + M[3][i]*M[3][j];
    }
    float V2[4][4];
    jacobi4(A2, V2, 4);
    float mu[4];
    #pragma unroll
    for (int i=0;i<4;++i) mu[i]=A2[i][i];
    #define CSW(I,J) if (mu[I] < mu[J]) { float tw; \
      tw=mu[I]; mu[I]=mu[J]; mu[J]=tw; \
      tw=V2[0][I]; V2[0][I]=V2[0][J]; V2[0][J]=tw; \
      tw=V2[1][I]; V2[1][I]=V2[1][J]; V2[1][J]=tw; \
      tw=V2[2][I]; V2[2][I]=V2[2][J]; V2[2][J]=tw; \
      tw=V2[3][I]; V2[3][I]=V2[3][J]; V2[3][J]=tw; }
    CSW(0,1) CSW(2,3) CSW(0,2) CSW(1,3) CSW(1,2)
    #undef CSW
    float u0[4],u1[4],u2[4];
    #pragma unroll
    for (int d=0;d<4;++d){
      u0[d]=M[d][0]*V2[0][0]+M[d][1]*V2[1][0]+M[d][2]*V2[2][0]+M[d][3]*V2[3][0];
      u1[d]=M[d][0]*V2[0][1]+M[d][1]*V2[1][1]+M[d][2]*V2[2][1]+M[d][3]*V2[3][1];
      u2[d]=M[d][0]*V2[0][2]+M[d][1]*V2[1][2]+M[d][2]*V2[2][2]+M[d][3]*V2[3][2];
    }
    {
      float dd = u0[0]*u0[0]+u0[1]*u0[1]+u0[2]*u0[2]+u0[3]*u0[3];
      float in0 = 1.0f/sqrtf(fmaxf(dd,1e-30f));
      #pragma unroll
      for (int d=0;d<4;++d) u0[d]*=in0;
      float p01 = u0[0]*u1[0]+u0[1]*u1[1]+u0[2]*u1[2]+u0[3]*u1[3];
      #pragma unroll
      for (int d=0;d<4;++d) u1[d]-=p01*u0[d];
      dd = u1[0]*u1[0]+u1[1]*u1[1]+u1[2]*u1[2]+u1[3]*u1[3];
      float in1 = 1.0f/sqrtf(fmaxf(dd,1e-30f));
      #pragma unroll
      for (int d=0;d<4;++d) u1[d]*=in1;
      float p02 = u0[0]*u2[0]+u0[1]*u2[1]+u0[2]*u2[2]+u0[3]*u2[3];
      float p12 = u1[0]*u2[0]+u1[1]*u2[1]+u1[2]*u2[2]+u1[3]*u2[3];
      #pragma unroll
      for (int d=0;d<4;++d) u2[d]-=p02*u0[d]+p12*u1[d];
      dd = u2[0]*u2[0]+u2[1]*u2[1]+u2[2]*u2[2]+u2[3]*u2[3];
      float in2 = 1.0f/sqrtf(fmaxf(dd,1e-30f));
      #pragma unroll
      for (int d=0;d<4;++d) u2[d]*=in2;
    }
    #define D3(p,q,r) (u0[p]*(u1[q]*u2[r]-u1[r]*u2[q]) - u1[p]*(u0[q]*u2[r]-u0[r]*u2[q]) + u2[p]*(u0[q]*u1[r]-u0[r]*u1[q]))
    float t3[4];
    t3[0] = -D3(1,2,3); t3[1] = D3(0,2,3); t3[2] = -D3(0,1,3); t3[3] = D3(0,1,2);
    #undef D3
    float dl = (det4(V2) >= 0.0f) ? 1.0f : -1.0f;
    float R[4][4];
    #pragma unroll
    for (int d=0;d<4;++d){
      #pragma unroll
      for (int e=0;e<4;++e)
        R[d][e] = u0[d]*V2[e][0] + u1[d]*V2[e][1] + u2[d]*V2[e][2] + dl*t3[d]*V2[e][3];
    }
    // reload parked Wm, T = R*Wm
    float Wr[4][4];
    Wr[0][0]=slot[0]; Wr[0][1]=Wr[1][0]=slot[1]; Wr[0][2]=Wr[2][0]=slot[2]; Wr[0][3]=Wr[3][0]=slot[3];
    Wr[1][1]=slot[4]; Wr[1][2]=Wr[2][1]=slot[5]; Wr[1][3]=Wr[3][1]=slot[6];
    Wr[2][2]=slot[7]; Wr[2][3]=Wr[3][2]=slot[8]; Wr[3][3]=slot[9];
    float T[4][4];
    mm44(T, R, Wr);
    #pragma unroll
    for (int d=0;d<4;++d){
      #pragma unroll
      for (int e=0;e<4;++e) slot[10+4*d+e]=T[d][e];
    }
  }
  __syncthreads();

  // ---- Phase 3: u + score (pass A), then accumulate e*Za (pass B, H re-read) ----
  const float b2v = b2[0];
  const int gFirst = batch[n0];
  if (valid){
    const float* slot = nodeMat + nq*NODE_STRIDE;   // quad-broadcast LDS reads
    const float* Hn = H + (size_t)node*256;
    float Wm[4][4];
    Wm[0][0]=slot[0]; Wm[0][1]=Wm[1][0]=slot[1]; Wm[0][2]=Wm[2][0]=slot[2]; Wm[0][3]=Wm[3][0]=slot[3];
    Wm[1][1]=slot[4]; Wm[1][2]=Wm[2][1]=slot[5]; Wm[1][3]=Wm[3][1]=slot[6];
    Wm[2][2]=slot[7]; Wm[2][3]=Wm[3][2]=slot[8]; Wm[3][3]=slot[9];
    // pass A: u[col] = |W h_col|^2 — no Za materialization
    float u[16];
    #pragma unroll
    for (int j=0;j<4;++j){
      float4 t0 = *(const float4*)(Hn + 0*64 + j*16 + iq*4);
      float4 t1 = *(const float4*)(Hn + 1*64 + j*16 + iq*4);
      float4 t2 = *(const float4*)(Hn + 2*64 + j*16 + iq*4);
      float4 t3 = *(const float4*)(Hn + 3*64 + j*16 + iq*4);
      #define UCOL(c, CMP) { \
        float x0=t0.CMP, x1=t1.CMP, x2=t2.CMP, x3=t3.CMP; \
        float w0 = Wm[0][0]*x0+Wm[0][1]*x1+Wm[0][2]*x2+Wm[0][3]*x3; \
        float w1v= Wm[1][0]*x0+Wm[1][1]*x1+Wm[1][2]*x2+Wm[1][3]*x3; \
        float w2v= Wm[2][0]*x0+Wm[2][1]*x1+Wm[2][2]*x2+Wm[2][3]*x3; \
        float w3 = Wm[3][0]*x0+Wm[3][1]*x1+Wm[3][2]*x2+Wm[3][3]*x3; \
        u[4*j+c] = w0*w0+w1v*w1v+w2v*w2v+w3*w3; }
      UCOL(0, x) UCOL(1, y) UCOL(2, z) UCOL(3, w)
      #undef UCOL
    }
    // MLP score: h1 = gelu(u @ w1 + b1), sp = h1 @ w2
    float h1[16];
    #pragma unroll
    for (int kk=0;kk<16;++kk) h1[kk]=b1L[iq*16+kk];
    for (int m=0;m<4;++m){
      int qq = iq ^ m;
      #pragma unroll
      for (int jl=0;jl<16;++jl){
        float uu = __shfl_xor(u[jl], m);
        int c = 16*(jl>>2) + 4*qq + (jl&3);
        const float* wr = w1L + c*64 + iq*16;
        float4 wA=*(const float4*)(wr);
        float4 wB=*(const float4*)(wr+4);
        float4 wC=*(const float4*)(wr+8);
        float4 wD=*(const float4*)(wr+12);
        h1[0]+=uu*wA.x; h1[1]+=uu*wA.y; h1[2]+=uu*wA.z; h1[3]+=uu*wA.w;
        h1[4]+=uu*wB.x; h1[5]+=uu*wB.y; h1[6]+=uu*wB.z; h1[7]+=uu*wB.w;
        h1[8]+=uu*wC.x; h1[9]+=uu*wC.y; h1[10]+=uu*wC.z; h1[11]+=uu*wC.w;
        h1[12]+=uu*wD.x; h1[13]+=uu*wD.y; h1[14]+=uu*wD.z; h1[15]+=uu*wD.w;
      }
    }
    float sp = 0.0f;
    #pragma unroll
    for (int kk=0;kk<16;++kk) sp += gelu_exact(h1[kk]) * w2L[iq*16+kk];
    sp += __shfl_xor(sp,1); sp += __shfl_xor(sp,2);
    float e = expf(sp + b2v);   // scores tiny -> no-max-shift softmax safe

    // pass B: recompute Za = T*h on the fly (H reload is L1/L2-hot), accumulate
    asm volatile("" ::: "memory");   // keep compiler from caching pass-A H loads
    float T[4][4];
    #pragma unroll
    for (int d=0;d<4;++d){
      #pragma unroll
      for (int e2=0;e2<4;++e2) T[d][e2]=slot[10+4*d+e2];
    }
    int g  = batch[node];
    int gl = g - gFirst;
    const int jo = (nq>>2)&3;   // per-quad column-group stagger
    if (gl < MAXG){
      float* acc = accL + gl*ACC_STRIDE;
      #pragma unroll
      for (int jj=0;jj<4;++jj){
        int j = (jj + jo)&3;
        float4 t0 = *(const float4*)(Hn + 0*64 + j*16 + iq*4);
        float4 t1 = *(const float4*)(Hn + 1*64 + j*16 + iq*4);
        float4 t2 = *(const float4*)(Hn + 2*64 + j*16 + iq*4);
        float4 t3 = *(const float4*)(Hn + 3*64 + j*16 + iq*4);
        float za[4], zb[4], zc[4], zd[4];
        #define ZCOL(c, CMP) { \
          float x0=t0.CMP, x1=t1.CMP, x2=t2.CMP, x3=t3.CMP; \
          za[c] = T[0][0]*x0+T[0][1]*x1+T[0][2]*x2+T[0][3]*x3; \
          zb[c] = T[1][0]*x0+T[1][1]*x1+T[1][2]*x2+T[1][3]*x3; \
          zc[c] = T[2][0]*x0+T[2][1]*x1+T[2][2]*x2+T[2][3]*x3; \
          zd[c] = T[3][0]*x0+T[3][1]*x1+T[3][2]*x2+T[3][3]*x3; }
        ZCOL(0, x) ZCOL(1, y) ZCOL(2, z) ZCOL(3, w)
        #undef ZCOL
        #pragma unroll
        for (int dd=0;dd<4;++dd){
          int dsel = (nq + dd) & 3;  // d-stagger: with j-stagger -> 64 distinct addrs/wave-op
          #pragma unroll
          for (int c=0;c<4;++c){
            float v = (dsel==0)?za[c] : (dsel==1)?zb[c] : (dsel==2)?zc[c] : zd[c];
            atomicAdd(acc + dsel*64 + 16*j + 4*iq + c, e*v);
          }
        }
      }
      if (iq==0) atomicAdd(acc + 256, e);
    } else {
      // pathological batch fallback: direct global atomics
      float* wsg = wsAcc + (size_t)g*WSG_STRIDE;
      #pragma unroll
      for (int jj=0;jj<4;++jj){
        int j = (jj + jo)&3;
        float4 t0 = *(const float4*)(Hn + 0*64 + j*16 + iq*4);
        float4 t1 = *(const float4*)(Hn + 1*64 + j*16 + iq*4);
        float4 t2 = *(const float4*)(Hn + 2*64 + j*16 + iq*4);
        float4 t3 = *(const float4*)(Hn + 3*64 + j*16 + iq*4);
        float za[4], zb[4], zc[4], zd[4];
        #define ZCOL(c, CMP) { \
          float x0=t0.CMP, x1=t1.CMP, x2=t2.CMP, x3=t3.CMP; \
          za[c] = T[0][0]*x0+T[0][1]*x1+T[0][2]*x2+T[0][3]*x3; \
          zb[c] = T[1][0]*x0+T[1][1]*x1+T[1][2]*x2+T[1][3]*x3; \
          zc[c] = T[2][0]*x0+T[2][1]*x1+T[2][2]*x2+T[2][3]*x3; \
          zd[c] = T[3][0]*x0+T[3][1]*x1+T[3][2]*x2+T[3][3]*x3; }
        ZCOL(0, x) ZCOL(1, y) ZCOL(2, z) ZCOL(3, w)
        #undef ZCOL
        #pragma unroll
        for (int dd=0;dd<4;++dd){
          #pragma unroll
          for (int c=0;c<4;++c){
            float v = (dd==0)?za[c] : (dd==1)?zb[c] : (dd==2)?zc[c] : zd[c];
            atomicAdd(wsg + dd*64 + 16*j + 4*iq + c, e*v);
          }
        }
      }
      if (iq==0) atomicAdd(wsg + 256, e);
    }
  }
  __syncthreads();

  // ---- flush LDS accumulators to global ----
  {
    int lastIdx = n0+NPB-1 < N ? n0+NPB-1 : N-1;
    int gLast = batch[lastIdx];
    int ngl = gLast - gFirst + 1; if (ngl > MAXG) ngl = MAXG;
    for (int idx=tid; idx<ngl*ACC_STRIDE; idx+=256){
      int gl = idx / ACC_STRIDE;
      int sl = idx - gl*ACC_STRIDE;
      float v = accL[idx];
      if (v != 0.0f) atomicAdd(wsAcc + (size_t)(gFirst+gl)*WSG_STRIDE + sl, v);
    }
  }
}

// ---------------- per-graph MLP + LayerNorm + reduce ----------------
__global__ __launch_bounds__(256) void finalize_kernel(
    const float* __restrict__ wsAcc, const float* __restrict__ token,
    const float* __restrict__ wc1, const float* __restrict__ bc1,
    const float* __restrict__ wc2, const float* __restrict__ bc2,
    const float* __restrict__ lng, const float* __restrict__ lnb,
    float* __restrict__ out)
{
  __shared__ float comb[4][128];
  __shared__ float hcL[4][64];
  __shared__ float upsq[4][64];
  const int g = blockIdx.x, tid = threadIdx.x;
  const int d = tid >> 6, k = tid & 63;
  const float* wsg = wsAcc + (size_t)g*WSG_STRIDE;
  float denom = wsg[256];
  float inv = (denom != 0.0f) ? 1.0f/denom : 0.0f;
  for (int i=tid;i<512;i+=256){
    int dd=i>>7, j=i&127;
    comb[dd][j] = (j<64) ? token[dd*64+j] : wsg[dd*64+(j-64)]*inv;
  }
  __syncthreads();
  float acc = bc1[k];
  for (int j=0;j<128;++j) acc += comb[d][j]*wc1[j*64+k];
  hcL[d][k] = gelu_exact(acc);
  __syncthreads();
  float acc2 = bc2[k];
  for (int j=0;j<64;++j) acc2 += hcL[d][j]*wc2[j*64+k];
  float s1 = acc2, s2 = acc2*acc2;
  #pragma unroll
  for (int m=1;m<64;m<<=1){ s1 += __shfl_xor(s1,m); s2 += __shfl_xor(s2,m); }
  float mu  = s1*(1.0f/64.0f);
  float var = s2*(1.0f/64.0f) - mu*mu;
  float up = (acc2 - mu)*(1.0f/sqrtf(var + 1e-5f))*lng[k] + lnb[k];
  upsq[d][k] = up*up;
  __syncthreads();
  if (tid < 64)
    out[(size_t)g*64 + tid] = upsq[0][tid]+upsq[1][tid]+upsq[2][tid]+upsq[3][tid];
}

extern "C" void kernel_launch(void* const* d_in, const int* in_sizes, int n_in,
                              void* d_out, int out_size, void* d_ws, size_t ws_size,
                              hipStream_t stream) {
  (void)n_in; (void)ws_size;
  const float* H      = (const float*)d_in[0];
  const int*   batch  = (const int*)  d_in[1];
  const float* anchor = (const float*)d_in[3];
  const float* w1     = (const float*)d_in[4];
  const float* b1     = (const float*)d_in[5];
  const float* w2     = (const float*)d_in[6];
  const float* b2     = (const float*)d_in[7];
  const float* token  = (const float*)d_in[8];
  const float* wc1    = (const float*)d_in[9];
  const float* bc1    = (const float*)d_in[10];
  const float* wc2    = (const float*)d_in[11];
  const float* bc2    = (const float*)d_in[12];
  const float* ln_g   = (const float*)d_in[13];
  const float* ln_b   = (const float*)d_in[14];
  float* out = (float*)d_out;

  const int N = in_sizes[0] / 256;   // nodes
  const int B = out_size / 64;       // graphs
  const int nb = (N + NPB - 1)/NPB;

  float* wsAcc = (float*)d_ws;       // B*WSG_STRIDE floats

  hipMemsetAsync(wsAcc, 0, (size_t)B*WSG_STRIDE*sizeof(float), stream);
  node_kernel<<<nb, 256, 0, stream>>>(H, batch, anchor, w1, b1, w2, b2, wsAcc, N);
  finalize_kernel<<<B, 256, 0, stream>>>(wsAcc, token, wc1, bc1, wc2, bc2, ln_g, ln_b, out);
}